// Round 1
// baseline (100.580 us; speedup 1.0000x reference)
//
#include <hip/hip_runtime.h>

// OrdinalCrossEntropyLoss: out = sum_n sum_{i < t_n} relu(logits[n,i] - logits[n,t_n])
// N = 262144 rows, C = 512 classes, fp32 logits, int targets, scalar fp32 out.
//
// Memory-bound. Only the prefix [0, t) of each row is needed -> read ~half
// the logits on average. One wave per row, float4 coalesced prefix loads.

constexpr int C = 512;

__global__ __launch_bounds__(256) void ordinal_ce_kernel(
    const float* __restrict__ logits,
    const int* __restrict__ targets,
    float* __restrict__ out,
    int N)
{
    const int lane    = threadIdx.x & 63;
    const int wave_id = (blockIdx.x * blockDim.x + threadIdx.x) >> 6;
    const int n_waves = (gridDim.x * blockDim.x) >> 6;

    float acc = 0.0f;

    for (int row = wave_id; row < N; row += n_waves) {
        const int t = targets[row];            // uniform across wave (broadcast)
        if (t <= 0) continue;                  // empty prefix
        const float* __restrict__ rp = logits + (size_t)row * C;
        const float tl = rp[t];                // target logit (broadcast load)

        // Prefix [0, t): lane handles floats [4*lane + 256*k, +4). Row start is
        // 2 KiB aligned so float4 loads are 16B-aligned and fully coalesced.
        for (int base = lane * 4; base < t; base += 256) {
            const float4 v = *reinterpret_cast<const float4*>(rp + base);
            if (base + 4 <= t) {
                acc += fmaxf(v.x - tl, 0.0f) + fmaxf(v.y - tl, 0.0f)
                     + fmaxf(v.z - tl, 0.0f) + fmaxf(v.w - tl, 0.0f);
            } else {
                // tail chunk straddling t
                if (base + 0 < t) acc += fmaxf(v.x - tl, 0.0f);
                if (base + 1 < t) acc += fmaxf(v.y - tl, 0.0f);
                if (base + 2 < t) acc += fmaxf(v.z - tl, 0.0f);
                // base+3 < t is impossible here (base+4 > t)
            }
        }
    }

    // Wave reduction (64 lanes)
    #pragma unroll
    for (int off = 32; off > 0; off >>= 1)
        acc += __shfl_down(acc, off, 64);

    // Block reduction: 4 waves / 256 threads
    __shared__ float wave_sums[4];
    const int wib = threadIdx.x >> 6;
    if (lane == 0) wave_sums[wib] = acc;
    __syncthreads();
    if (threadIdx.x == 0) {
        const float s = wave_sums[0] + wave_sums[1] + wave_sums[2] + wave_sums[3];
        atomicAdd(out, s);
    }
}

extern "C" void kernel_launch(void* const* d_in, const int* in_sizes, int n_in,
                              void* d_out, int out_size, void* d_ws, size_t ws_size,
                              hipStream_t stream) {
    const float* logits  = (const float*)d_in[0];
    const int*   targets = (const int*)d_in[1];
    float*       out     = (float*)d_out;

    const int N = in_sizes[1];                 // 262144 rows

    // d_out is poisoned (0xAA) before timing and NOT re-poisoned between
    // replays; we accumulate with atomics, so zero it every call.
    hipMemsetAsync(out, 0, sizeof(float) * out_size, stream);

    const int block = 256;
    const int grid  = 2048;                    // 8192 waves, 32 rows/wave
    ordinal_ce_kernel<<<grid, block, 0, stream>>>(logits, targets, out, N);
}

// Round 2
// 91.681 us; speedup vs baseline: 1.0971x; 1.0971x over previous
//
#include <hip/hip_runtime.h>

// OrdinalCrossEntropyLoss: out = sum_n sum_{i < t_n} relu(logits[n,i] - logits[n,t_n])
// N = 262144 rows, C = 512 classes, fp32 logits, int targets, scalar fp32 out.
//
// Memory-bound; read only the prefix [0,t) of each row (~half the bytes).
// R1 lesson: per-row dependent chain (targets[row] -> t -> prefix loads)
// serialized ~2 HBM latencies per row. Fix: wave preloads 32 rows' targets
// (coalesced) + target-logits (32 parallel gathers) up front; t/tl then come
// from registers via shfl, so the prefix streaming loop is dependency-free.

constexpr int C = 512;
constexpr int ROWS_PER_WAVE = 32;

__global__ __launch_bounds__(256) void ordinal_ce_kernel(
    const float* __restrict__ logits,
    const int* __restrict__ targets,
    float* __restrict__ out,
    int N)
{
    const int lane    = threadIdx.x & 63;
    const int wave_id = (blockIdx.x * blockDim.x + threadIdx.x) >> 6;
    const int rowbase = wave_id * ROWS_PER_WAVE;

    float acc = 0.0f;

    if (rowbase < N) {
        // --- metadata preload: lanes 0..31 each own one row of this chunk ---
        int   t_l  = 0;
        float tl_l = 0.0f;
        if (lane < ROWS_PER_WAVE && rowbase + lane < N) {
            const int r = rowbase + lane;
            t_l  = targets[r];                               // coalesced 128B
            tl_l = logits[(size_t)r * C + t_l];              // 32 gathers in flight
        }

        // --- prefix streaming: all bounds/operands in registers ---
        const int rows = (N - rowbase < ROWS_PER_WAVE) ? (N - rowbase) : ROWS_PER_WAVE;
        for (int r = 0; r < rows; ++r) {
            const int   t  = __shfl(t_l, r, 64);
            const float tl = __shfl(tl_l, r, 64);
            if (t <= 0) continue;
            const float* __restrict__ rp = logits + (size_t)(rowbase + r) * C;

            // lane covers floats [4*lane + 256*k, +4); row is 2KiB-aligned.
            for (int base = lane * 4; base < t; base += 256) {
                const float4 v = *reinterpret_cast<const float4*>(rp + base);
                if (base + 4 <= t) {
                    acc += fmaxf(v.x - tl, 0.0f) + fmaxf(v.y - tl, 0.0f)
                         + fmaxf(v.z - tl, 0.0f) + fmaxf(v.w - tl, 0.0f);
                } else {
                    if (base + 0 < t) acc += fmaxf(v.x - tl, 0.0f);
                    if (base + 1 < t) acc += fmaxf(v.y - tl, 0.0f);
                    if (base + 2 < t) acc += fmaxf(v.z - tl, 0.0f);
                }
            }
        }
    }

    // --- wave reduction (64 lanes) ---
    #pragma unroll
    for (int off = 32; off > 0; off >>= 1)
        acc += __shfl_down(acc, off, 64);

    // --- block reduction: 4 waves ---
    __shared__ float wave_sums[4];
    const int wib = threadIdx.x >> 6;
    if (lane == 0) wave_sums[wib] = acc;
    __syncthreads();
    if (threadIdx.x == 0) {
        const float s = wave_sums[0] + wave_sums[1] + wave_sums[2] + wave_sums[3];
        atomicAdd(out, s);
    }
}

extern "C" void kernel_launch(void* const* d_in, const int* in_sizes, int n_in,
                              void* d_out, int out_size, void* d_ws, size_t ws_size,
                              hipStream_t stream) {
    const float* logits  = (const float*)d_in[0];
    const int*   targets = (const int*)d_in[1];
    float*       out     = (float*)d_out;

    const int N = in_sizes[1];                 // 262144 rows

    // d_out is poisoned and not re-poisoned between replays; we accumulate.
    hipMemsetAsync(out, 0, sizeof(float) * out_size, stream);

    const int block = 256;
    const int rows_per_block = (block / 64) * ROWS_PER_WAVE;   // 128
    const int grid = (N + rows_per_block - 1) / rows_per_block; // 2048
    ordinal_ce_kernel<<<grid, block, 0, stream>>>(logits, targets, out, N);
}

// Round 3
// 65.447 us; speedup vs baseline: 1.5368x; 1.4008x over previous
//
#include <hip/hip_runtime.h>

// OrdinalCrossEntropyLoss: out = sum_n sum_{i < t_n} relu(logits[n,i] - logits[n,t_n])
// N = 262144 rows, C = 512 classes, fp32 logits, int targets, scalar fp32 out.
//
// Memory-bound; read only the prefix [0,t) of each row (~half the bytes).
// R2 lesson: dynamic inner-loop bound (base < t) serialized chunk loads
// (vmcnt(0) between chunks). Fix: static 2-chunk structure (C=512 = 2 x
// 256-float wave chunks), 4 rows per step, all 8 predicated loads issued
// before any consumption (sched_barrier pins the order) -> ~8 loads/lane
// in flight instead of ~1.

constexpr int C = 512;
constexpr int ROWS_PER_WAVE = 32;
constexpr int RSTEP = 4;

__device__ __forceinline__ float contrib4(const float4 v, int i, int t, float tl) {
    float s = 0.0f;
    s += (i + 0 < t) ? fmaxf(v.x - tl, 0.0f) : 0.0f;
    s += (i + 1 < t) ? fmaxf(v.y - tl, 0.0f) : 0.0f;
    s += (i + 2 < t) ? fmaxf(v.z - tl, 0.0f) : 0.0f;
    s += (i + 3 < t) ? fmaxf(v.w - tl, 0.0f) : 0.0f;
    return s;
}

__global__ __launch_bounds__(256) void ordinal_ce_kernel(
    const float* __restrict__ logits,
    const int* __restrict__ targets,
    float* __restrict__ out,
    int N)
{
    const int lane    = threadIdx.x & 63;
    const int wave_id = (blockIdx.x * blockDim.x + threadIdx.x) >> 6;
    const int rowbase = wave_id * ROWS_PER_WAVE;

    float acc = 0.0f;

    if (rowbase < N) {
        // --- metadata preload: lanes 0..31 each own one row of this chunk ---
        int   t_l  = 0;
        float tl_l = 0.0f;
        if (lane < ROWS_PER_WAVE && rowbase + lane < N) {
            const int r = rowbase + lane;
            t_l  = targets[r];                               // coalesced 128B
            tl_l = logits[(size_t)r * C + t_l];              // 32 gathers in flight
        }

        const int i0 = lane * 4;         // chunk-0 element index for this lane
        const int i1 = lane * 4 + 256;   // chunk-1 element index

        // N % (ROWS_PER_WAVE * waves/block) == 0 for this problem, but keep
        // the general bound cheap.
        const int rows = (N - rowbase < ROWS_PER_WAVE) ? (N - rowbase) : ROWS_PER_WAVE;

        for (int r0 = 0; r0 + RSTEP <= rows; r0 += RSTEP) {
            int   t[RSTEP];
            float tl[RSTEP];
            #pragma unroll
            for (int k = 0; k < RSTEP; ++k) {
                t[k]  = __shfl(t_l,  r0 + k, 64);
                tl[k] = __shfl(tl_l, r0 + k, 64);
            }

            float4 c0[RSTEP], c1[RSTEP];
            #pragma unroll
            for (int k = 0; k < RSTEP; ++k) {
                const float* __restrict__ rp =
                    logits + (size_t)(rowbase + r0 + k) * C;
                c0[k] = make_float4(0.f, 0.f, 0.f, 0.f);
                c1[k] = make_float4(0.f, 0.f, 0.f, 0.f);
                if (i0 < t[k]) c0[k] = *reinterpret_cast<const float4*>(rp + i0);
                if (i1 < t[k]) c1[k] = *reinterpret_cast<const float4*>(rp + i1);
            }

            // Pin: all 8 loads issued before any accumulate consumes them.
            __builtin_amdgcn_sched_barrier(0);

            #pragma unroll
            for (int k = 0; k < RSTEP; ++k) {
                acc += contrib4(c0[k], i0, t[k], tl[k]);
                acc += contrib4(c1[k], i1, t[k], tl[k]);
            }
        }

        // tail rows (rows not a multiple of RSTEP) — doesn't trigger here
        for (int r = rows & ~(RSTEP - 1); r < rows; ++r) {
            const int   t  = __shfl(t_l,  r, 64);
            const float tl = __shfl(tl_l, r, 64);
            const float* __restrict__ rp = logits + (size_t)(rowbase + r) * C;
            float4 c0 = make_float4(0.f, 0.f, 0.f, 0.f);
            float4 c1 = make_float4(0.f, 0.f, 0.f, 0.f);
            if (i0 < t) c0 = *reinterpret_cast<const float4*>(rp + i0);
            if (i1 < t) c1 = *reinterpret_cast<const float4*>(rp + i1);
            acc += contrib4(c0, i0, t, tl) + contrib4(c1, i1, t, tl);
        }
    }

    // --- wave reduction (64 lanes) ---
    #pragma unroll
    for (int off = 32; off > 0; off >>= 1)
        acc += __shfl_down(acc, off, 64);

    // --- block reduction: 4 waves ---
    __shared__ float wave_sums[4];
    const int wib = threadIdx.x >> 6;
    if (lane == 0) wave_sums[wib] = acc;
    __syncthreads();
    if (threadIdx.x == 0) {
        const float s = wave_sums[0] + wave_sums[1] + wave_sums[2] + wave_sums[3];
        atomicAdd(out, s);
    }
}

extern "C" void kernel_launch(void* const* d_in, const int* in_sizes, int n_in,
                              void* d_out, int out_size, void* d_ws, size_t ws_size,
                              hipStream_t stream) {
    const float* logits  = (const float*)d_in[0];
    const int*   targets = (const int*)d_in[1];
    float*       out     = (float*)d_out;

    const int N = in_sizes[1];                 // 262144 rows

    // d_out is poisoned and not re-poisoned between replays; we accumulate.
    hipMemsetAsync(out, 0, sizeof(float) * out_size, stream);

    const int block = 256;
    const int rows_per_block = (block / 64) * ROWS_PER_WAVE;    // 128
    const int grid = (N + rows_per_block - 1) / rows_per_block; // 2048
    ordinal_ce_kernel<<<grid, block, 0, stream>>>(logits, targets, out, N);
}